// Round 8
// baseline (438.274 us; speedup 1.0000x reference)
//
#include <hip/hip_runtime.h>
#include <hip/hip_bf16.h>
#include <cstdint>

// Problem constants
#define BB 4
#define TT 2048
#define EE 1024
#define HH 16
#define DD 64
#define BH (BB*HH)       // 64
#define MM (BB*TT)       // 8192 rows for projection GEMMs
#define KK 1024          // contraction dim for projections
#define KSTR 72          // flash K-tile LDS row stride (ushorts)
#define VSTR 136         // flash V-tile LDS row stride (ushorts)
#define LOG2E 1.44269504088896340736f

typedef __attribute__((ext_vector_type(8))) short short8;    // 8 x bf16
typedef __attribute__((ext_vector_type(4))) short short4_;   // 4 x bf16
typedef __attribute__((ext_vector_type(4))) float float4_;   // MFMA accumulator
typedef __attribute__((ext_vector_type(4))) ushort ushort4_;

__device__ __forceinline__ void gl_lds16(const void* g, void* l) {
    __builtin_amdgcn_global_load_lds(
        (const __attribute__((address_space(1))) void*)g,
        (__attribute__((address_space(3))) void*)l, 16, 0, 0);
}

__device__ __forceinline__ ushort f2bf(float v) {
    __hip_bfloat16 h = __float2bfloat16(v);
    return *(ushort*)&h;
}

// ---------------------------------------------------------------------------
// fp32 -> bf16 conversion (weights only). grid.y selects segment.
// ---------------------------------------------------------------------------
__global__ __launch_bounds__(256) void cvt_kernel(
    const float* __restrict__ s0, ushort* __restrict__ d0, int n0,
    const float* __restrict__ s1, ushort* __restrict__ d1, int n1,
    const float* __restrict__ s2, ushort* __restrict__ d2, int n2,
    const float* __restrict__ s3, ushort* __restrict__ d3, int n3)
{
    const float* s; ushort* d; int n;
    switch (blockIdx.y) {
        case 0: s = s0; d = d0; n = n0; break;
        case 1: s = s1; d = d1; n = n1; break;
        case 2: s = s2; d = d2; n = n2; break;
        default: s = s3; d = d3; n = n3; break;
    }
    int i = (blockIdx.x * 256 + threadIdx.x) * 4;
    if (i >= n) return;
    float4_ v = *(const float4_*)&s[i];
    ushort4_ o;
#pragma unroll
    for (int j = 0; j < 4; j++) o[j] = f2bf(v[j]);
    *(ushort4_*)&d[i] = o;
}

// ---------------------------------------------------------------------------
// MERGED Q/K/V projection GEMM.  blockIdx.z selects {A, W, bias, out, scale,
// scatter-mode}.
//
// Round-8 change: BK=64 (was 32).  Round-7 counters showed gemm_qkv is
// latency-bound on the per-k-step serial path (MfmaUtil 13%, VALUBusy 10%,
// HBM 10% after swizzle — nothing busy): each k-step pays 2 barriers + a
// vmcnt(0)+lgkmcnt(0) drain of the just-issued W gl_lds, and the A-prefetch's
// ~300cy L2 latency doesn't fit under ~150cy of compute (m233: at 2-phase,
// stage+vmcnt+barrier is ~72% of critical path).  BK=64 halves the number of
// drains (16 k-steps) and doubles the compute window per step, covering the
// A-prefetch latency.  LDS 32 KB -> still 3 blocks/CU.  XCD swizzle reverted
// (round-7: traffic -6x but time +5% — kernel is not HBM-bound; T1/m160).
//
// Staging hybrid (round-5 lesson, m151/T14): W via global_load_lds (fast
// path); A (fp32) register-prefetch + fused cvt (keeps input cvt kernels
// and the X0 round trip deleted).
// C[n,e] = (sum_k A[n,k]*W[e,k] + bias[e])*scale
// z=0,1: scatter bf16 per-head [B*H, T, D];  z=2: transposed [B*H, D, T].
// ---------------------------------------------------------------------------
__global__ __launch_bounds__(256, 3) void gemm_qkv(
    const float* __restrict__ Aq, const float* __restrict__ Ak,
    const float* __restrict__ Av,
    const ushort* __restrict__ Wqc, const ushort* __restrict__ Wkc,
    const ushort* __restrict__ Wvc,
    const float* __restrict__ bq, const float* __restrict__ bk,
    const float* __restrict__ bv,
    ushort* __restrict__ Oq, ushort* __restrict__ Ok, ushort* __restrict__ Ov,
    float qscale)
{
    __shared__ __align__(16) ushort As[128*64];   // 16 KB
    __shared__ __align__(16) ushort Bs[128*64];   // 16 KB

    const int z = blockIdx.z;
    const float*  A    = (z == 0) ? Aq  : (z == 1) ? Ak  : Av;
    const ushort* W    = (z == 0) ? Wqc : (z == 1) ? Wkc : Wvc;
    const float*  bias = (z == 0) ? bq  : (z == 1) ? bk  : bv;
    ushort*       Cout = (z == 0) ? Oq  : (z == 1) ? Ok  : Ov;
    const float   scale = (z == 0) ? qscale : 1.0f;
    const bool    modeT = (z == 2);

    const int tid  = threadIdx.x;
    const int wave = tid >> 6;
    const int lane = tid & 63;
    const int l15  = lane & 15;
    const int quad = lane >> 4;
    const int wm   = wave & 1;   // row half
    const int wn   = wave >> 1;  // col half

    const long rowBase = (long)blockIdx.y * 128;
    const long colBase = (long)blockIdx.x * 128;

    // staging geometry (BK=64): idx = it*256+tid, it=0..3;
    // r = idx>>3 (tile row 0..127), c8 = (idx&7)*8 (k chunk, 8 bf16 = 16B)
    int sr[4], sc[4];
#pragma unroll
    for (int it = 0; it < 4; it++) {
        int idx = it * 256 + tid;
        sr[it] = idx >> 3;
        sc[it] = (idx & 7) * 8;
    }

    // prologue: A k=0 into registers (with fused cvt)
    short8 pa[4];
#pragma unroll
    for (int it = 0; it < 4; it++) {
        const float* Arow = A + (rowBase + sr[it]) * KK + sc[it];
        float4_ f0 = *(const float4_*)&Arow[0];
        float4_ f1 = *(const float4_*)&Arow[4];
#pragma unroll
        for (int j = 0; j < 4; j++) {
            pa[it][j]     = (short)f2bf(f0[j]);
            pa[it][j + 4] = (short)f2bf(f1[j]);
        }
    }

    float4_ acc[4][4];
#pragma unroll
    for (int i = 0; i < 4; i++)
#pragma unroll
        for (int j = 0; j < 4; j++) acc[i][j] = float4_{0.f, 0.f, 0.f, 0.f};

    for (int k0 = 0; k0 < KK; k0 += 64) {
        __syncthreads();   // previous k-step's LDS reads done
#pragma unroll
        for (int it = 0; it < 4; it++) {
            int idx = it * 256 + tid;
            *(short8*)&As[idx * 8] = pa[it];
            gl_lds16(W + (colBase + sr[it]) * KK + k0 + sc[it], &Bs[idx * 8]);
        }
        __syncthreads();

        // prefetch next A k-step (latency hides under 2x32 MFMAs below)
        if (k0 + 64 < KK) {
            const int kn = k0 + 64;
#pragma unroll
            for (int it = 0; it < 4; it++) {
                const float* Arow = A + (rowBase + sr[it]) * KK + kn + sc[it];
                float4_ f0 = *(const float4_*)&Arow[0];
                float4_ f1 = *(const float4_*)&Arow[4];
#pragma unroll
                for (int j = 0; j < 4; j++) {
                    pa[it][j]     = (short)f2bf(f0[j]);
                    pa[it][j + 4] = (short)f2bf(f1[j]);
                }
            }
        }

#pragma unroll
        for (int kk = 0; kk < 2; kk++) {
            short8 af[4], bf[4];
#pragma unroll
            for (int mt = 0; mt < 4; mt++)
                af[mt] = *(const short8*)&As[(wm*64 + mt*16 + l15) * 64 + kk*32 + quad*8];
#pragma unroll
            for (int nt = 0; nt < 4; nt++)
                bf[nt] = *(const short8*)&Bs[(wn*64 + nt*16 + l15) * 64 + kk*32 + quad*8];
#pragma unroll
            for (int mt = 0; mt < 4; mt++)
#pragma unroll
                for (int nt = 0; nt < 4; nt++)
                    acc[mt][nt] = __builtin_amdgcn_mfma_f32_16x16x32_bf16(
                        af[mt], bf[nt], acc[mt][nt], 0, 0, 0);
        }
    }

    // Epilogue: C/D layout col = lane&15, row = quad*4 + reg
#pragma unroll
    for (int nt = 0; nt < 4; nt++) {
        const long col = colBase + wn*64 + nt*16 + l15;
        const float bvv = bias[col];
        const long h = col >> 6, d = col & (DD - 1);
#pragma unroll
        for (int mt = 0; mt < 4; mt++) {
            const long row0 = rowBase + wm*64 + mt*16 + quad*4;
            if (modeT) {
                const long b = row0 >> 11, t0 = row0 & (TT - 1);
                ushort4_ pk;
#pragma unroll
                for (int i = 0; i < 4; i++) pk[i] = f2bf((acc[mt][nt][i] + bvv) * scale);
                *(ushort4_*)&Cout[((b*HH + h)*DD + d)*TT + t0] = pk;
            } else {
#pragma unroll
                for (int i = 0; i < 4; i++) {
                    const long row = row0 + i;
                    const long b = row >> 11, t = row & (TT - 1);
                    Cout[(((b*HH + h) * TT) + t) * DD + d] =
                        f2bf((acc[mt][nt][i] + bvv) * scale);
                }
            }
        }
    }
}

// ---------------------------------------------------------------------------
// Output GEMM: BK=64, pure gl_lds staging both operands.
// C fp32 row-major [MM, EE] = (AO @ Wo^T + bo)
// ---------------------------------------------------------------------------
__global__ __launch_bounds__(256, 3) void gemm_out(
    const ushort* __restrict__ A, const ushort* __restrict__ W,
    const float* __restrict__ bias, float* __restrict__ Cout)
{
    __shared__ __align__(16) ushort As[128*64];
    __shared__ __align__(16) ushort Bs[128*64];

    const int tid  = threadIdx.x;
    const int wave = tid >> 6;
    const int lane = tid & 63;
    const int l15  = lane & 15;
    const int quad = lane >> 4;
    const int wm   = wave & 1;
    const int wn   = wave >> 1;

    const long rowBase = (long)blockIdx.y * 128;
    const long colBase = (long)blockIdx.x * 128;

    float4_ acc[4][4];
#pragma unroll
    for (int i = 0; i < 4; i++)
#pragma unroll
        for (int j = 0; j < 4; j++) acc[i][j] = float4_{0.f, 0.f, 0.f, 0.f};

    for (int k0 = 0; k0 < KK; k0 += 64) {
        __syncthreads();
#pragma unroll
        for (int it = 0; it < 4; it++) {
            int idx = it * 256 + tid;
            int r   = idx >> 3;
            int c8  = (idx & 7) * 8;
            gl_lds16(A + (rowBase + r) * KK + k0 + c8, &As[idx * 8]);
            gl_lds16(W + (colBase + r) * KK + k0 + c8, &Bs[idx * 8]);
        }
        __syncthreads();

#pragma unroll
        for (int kk = 0; kk < 2; kk++) {
            short8 af[4], bf[4];
#pragma unroll
            for (int mt = 0; mt < 4; mt++)
                af[mt] = *(const short8*)&As[(wm*64 + mt*16 + l15) * 64 + kk*32 + quad*8];
#pragma unroll
            for (int nt = 0; nt < 4; nt++)
                bf[nt] = *(const short8*)&Bs[(wn*64 + nt*16 + l15) * 64 + kk*32 + quad*8];
#pragma unroll
            for (int mt = 0; mt < 4; mt++)
#pragma unroll
                for (int nt = 0; nt < 4; nt++)
                    acc[mt][nt] = __builtin_amdgcn_mfma_f32_16x16x32_bf16(
                        af[mt], bf[nt], acc[mt][nt], 0, 0, 0);
        }
    }

#pragma unroll
    for (int nt = 0; nt < 4; nt++) {
        const long col = colBase + wn*64 + nt*16 + l15;
        const float bv = bias[col];
#pragma unroll
        for (int mt = 0; mt < 4; mt++) {
            const long row0 = rowBase + wm*64 + mt*16 + quad*4;
#pragma unroll
            for (int i = 0; i < 4; i++)
                Cout[(row0 + i) * EE + col] = acc[mt][nt][i] + bv;
        }
    }
}

// ---------------------------------------------------------------------------
// Flash attention (causal). Q,K: [B*H, T, D] bf16; Vt: [B*H, D, T] bf16;
// AO: [B, T, E] bf16.  Q pre-scaled by 0.125*log2(e) -> softmax via exp2.
// (Unchanged: operand-swapped S^T = mfma(K,Q), scalar softmax state, P in
// registers, LDS 35.8 KB, launch_bounds (512,4).)
// ---------------------------------------------------------------------------
__global__ __launch_bounds__(512, 4) void flash_kernel(
    const ushort* __restrict__ Qh, const ushort* __restrict__ Kh,
    const ushort* __restrict__ Vt, ushort* __restrict__ AO)
{
    __shared__ __align__(16) ushort Ks[128*KSTR];    // [key][d]     18.4 KB
    __shared__ __align__(16) ushort Vs[64*VSTR];     // [d][key]     17.4 KB

    const int qt  = (TT/128 - 1) - blockIdx.x;  // heavy tiles dispatch first
    const int bh  = blockIdx.y;                 // b*H + h
    const int tid = threadIdx.x;
    const int wave = tid >> 6, lane = tid & 63;
    const int l15 = lane & 15, quad = lane >> 4;

    const ushort* Qb = Qh + (long)bh * TT * DD;
    const ushort* Kb = Kh + (long)bh * TT * DD;
    const ushort* Vb = Vt + (long)bh * DD * TT;

    // This lane's q-row (B-fragment of swapped QK^T; also the output t)
    const int qrow = qt*128 + wave*16 + l15;
    short8 aq0 = *(const short8*)&Qb[(long)qrow * DD + quad*8];
    short8 aq1 = *(const short8*)&Qb[(long)qrow * DD + 32 + quad*8];

    // O^T accumulator: o[nt][i] = O[q=qrow][d = nt*16 + quad*4 + i]
    float4_ o[4];
#pragma unroll
    for (int nt = 0; nt < 4; nt++) o[nt] = float4_{0.f, 0.f, 0.f, 0.f};
    float m_run = -INFINITY, l_run = 0.0f;      // scalar per lane (one q-row)

    const int nkt = qt + 1;                    // number of 128-key tiles

    // prefetch tile 0 into registers (K: 128x64, V^T: 64x128)
    short8 kreg[2], vreg[2];
#pragma unroll
    for (int it = 0; it < 2; it++) {
        int c = it * 512 + tid;                    // 0..1023
        int kk = c >> 3, ks = c & 7;               // K: key, 16B seg
        kreg[it] = *(const short8*)&Kb[(long)kk * DD + ks*8];
        int dd = c >> 4, vs = c & 15;              // V: d, 16B seg
        vreg[it] = *(const short8*)&Vb[(long)dd * TT + vs*8];
    }

    for (int kt = 0; kt < nkt; kt++) {
        __syncthreads();   // previous tile's LDS reads done
#pragma unroll
        for (int it = 0; it < 2; it++) {
            int c = it * 512 + tid;
            int kk = c >> 3, ks = c & 7;
            *(short8*)&Ks[kk*KSTR + ks*8] = kreg[it];
            int dd = c >> 4, vs = c & 15;
            *(short8*)&Vs[dd*VSTR + vs*8] = vreg[it];
        }
        __syncthreads();

        // prefetch next tile (latency overlaps all compute below)
        if (kt + 1 < nkt) {
            const long koff = (long)(kt+1) * 128;
#pragma unroll
            for (int it = 0; it < 2; it++) {
                int c = it * 512 + tid;
                int kk = c >> 3, ks = c & 7;
                kreg[it] = *(const short8*)&Kb[(koff + kk) * DD + ks*8];
                int dd = c >> 4, vs = c & 15;
                vreg[it] = *(const short8*)&Vb[(long)dd * TT + koff + vs*8];
            }
        }

        // S^T = mfma(K, Q): col = q = l15, row = key = quad*4 + i
        float4_ s[8];
        __builtin_amdgcn_s_setprio(1);
#pragma unroll
        for (int nt = 0; nt < 8; nt++) {
            short8 bk0 = *(const short8*)&Ks[(nt*16 + l15) * KSTR + quad*8];
            short8 bk1 = *(const short8*)&Ks[(nt*16 + l15) * KSTR + 32 + quad*8];
            float4_ acc = float4_{0.f, 0.f, 0.f, 0.f};
            acc = __builtin_amdgcn_mfma_f32_16x16x32_bf16(bk0, aq0, acc, 0,0,0);
            acc = __builtin_amdgcn_mfma_f32_16x16x32_bf16(bk1, aq1, acc, 0,0,0);
            s[nt] = acc;
        }
        __builtin_amdgcn_s_setprio(0);

        if (kt == nkt - 1) {   // only the diagonal tile crosses the mask
#pragma unroll
            for (int nt = 0; nt < 8; nt++) {
#pragma unroll
                for (int i = 0; i < 4; i++) {
                    const int key = kt*128 + nt*16 + quad*4 + i;
                    if (key > qrow) s[nt][i] = -INFINITY;
                }
            }
        }

        // row max: in-register tree over this lane's 32 keys + cross-quad shfl
        float t8[8];
#pragma unroll
        for (int nt = 0; nt < 8; nt++)
            t8[nt] = fmaxf(fmaxf(s[nt][0], s[nt][1]), fmaxf(s[nt][2], s[nt][3]));
        float pm = fmaxf(fmaxf(fmaxf(t8[0], t8[1]), fmaxf(t8[2], t8[3])),
                         fmaxf(fmaxf(t8[4], t8[5]), fmaxf(t8[6], t8[7])));
        pm = fmaxf(pm, __shfl_xor(pm, 16));
        pm = fmaxf(pm, __shfl_xor(pm, 32));

        // T13 defer-max: skip rescale if max grew by < 8 (log2 domain, <=2^8)
        if (!__all(pm <= m_run + 8.0f)) {
            const float mnew = fmaxf(m_run, pm);
            const float alpha = exp2f(m_run - mnew);   // 0 on first tile
            m_run = mnew;
            l_run *= alpha;
#pragma unroll
            for (int nt = 0; nt < 4; nt++)
#pragma unroll
                for (int i = 0; i < 4; i++) o[nt][i] *= alpha;
        }

        // P = exp2(S - m): accumulate row sum and pack to bf16 immediately
        float rs0 = 0.f, rs1 = 0.f, rs2 = 0.f, rs3 = 0.f;
        short8 pb[4];
#pragma unroll
        for (int c = 0; c < 4; c++) {
#pragma unroll
            for (int half = 0; half < 2; half++) {
                const int nt = 2*c + half;
                const float p0 = exp2f(s[nt][0] - m_run);  // masked -> 0
                const float p1 = exp2f(s[nt][1] - m_run);
                const float p2 = exp2f(s[nt][2] - m_run);
                const float p3 = exp2f(s[nt][3] - m_run);
                rs0 += p0; rs1 += p1; rs2 += p2; rs3 += p3;
                pb[c][half*4 + 0] = (short)f2bf(p0);
                pb[c][half*4 + 1] = (short)f2bf(p1);
                pb[c][half*4 + 2] = (short)f2bf(p2);
                pb[c][half*4 + 3] = (short)f2bf(p3);
            }
        }
        float rs = (rs0 + rs1) + (rs2 + rs3);
        rs += __shfl_xor(rs, 16);
        rs += __shfl_xor(rs, 32);
        l_run += rs;

        // O^T += V^T @ P^T, P straight from registers.
        // k-slot (quad,j) -> key (2c + (j>>2))*16 + quad*4 + (j&3); V reads
        // use the same mapping: two b64 loads per output tile.
        __builtin_amdgcn_s_setprio(1);
#pragma unroll
        for (int c = 0; c < 4; c++) {
            const short8 bp = pb[c];
#pragma unroll
            for (int nt = 0; nt < 4; nt++) {
                const ushort* vrow = &Vs[(nt*16 + l15) * VSTR];
                short4_ lo = *(const short4_*)&vrow[(2*c    )*16 + quad*4];
                short4_ hi = *(const short4_*)&vrow[(2*c + 1)*16 + quad*4];
                short8 av;
                av[0]=lo[0]; av[1]=lo[1]; av[2]=lo[2]; av[3]=lo[3];
                av[4]=hi[0]; av[5]=hi[1]; av[6]=hi[2]; av[7]=hi[3];
                o[nt] = __builtin_amdgcn_mfma_f32_16x16x32_bf16(av, bp, o[nt], 0,0,0);
            }
        }
        __builtin_amdgcn_s_setprio(0);
    }

    // epilogue: AO[b, t=qrow, h*64 + d] = o / l ; d = nt*16 + quad*4 + i
    const int h = bh & (HH - 1);
    const int b = bh >> 4;
    const float inv = 1.0f / l_run;
    const long rowOff = ((long)(b*TT + qrow)) * EE + h*64;
#pragma unroll
    for (int nt = 0; nt < 4; nt++) {
        ushort4_ pk;
#pragma unroll
        for (int i = 0; i < 4; i++) pk[i] = f2bf(o[nt][i] * inv);
        *(ushort4_*)&AO[rowOff + nt*16 + quad*4] = pk;
    }
}

// ---------------------------------------------------------------------------
extern "C" void kernel_launch(void* const* d_in, const int* in_sizes, int n_in,
                              void* d_out, int out_size, void* d_ws, size_t ws_size,
                              hipStream_t stream)
{
    const float* query  = (const float*)d_in[0];
    const float* key_in = (const float*)d_in[1];
    const float* value  = (const float*)d_in[2];
    // d_in[3] = mask (int32 tril) — causal is hard-coded in flash_kernel
    const float* Wq = (const float*)d_in[4];
    const float* bq = (const float*)d_in[5];
    const float* Wk = (const float*)d_in[6];
    const float* bk = (const float*)d_in[7];
    const float* Wv = (const float*)d_in[8];
    const float* bv = (const float*)d_in[9];
    const float* Wo = (const float*)d_in[10];
    const float* bo = (const float*)d_in[11];

    ushort* ws = (ushort*)d_ws;
    const size_t NIN = (size_t)MM * KK;        // 8,388,608 elems
    const size_t NW  = (size_t)EE * KK;        // 1,048,576 elems (weights)
    ushort* Wqc = ws;                          // 2 MB each
    ushort* Wkc = Wqc + NW;
    ushort* Wvc = Wkc + NW;
    ushort* Woc = Wvc + NW;
    ushort* Qh  = Woc + NW;                    // 16 MB  [bh][t][d], pre-scaled
    ushort* Kh  = Qh + NIN;                    // 16 MB  [bh][t][d]
    ushort* Vth = Kh + NIN;                    // 16 MB  [bh][d][t]
    ushort* AO  = Vth + NIN;                   // 16 MB  [b][t][e]  (total 72 MB)

    const dim3 cvtW_grid(NW/1024, 4);

    // weights -> bf16 (one batched launch)
    cvt_kernel<<<cvtW_grid, 256, 0, stream>>>(Wq, Wqc, (int)NW, Wk, Wkc, (int)NW,
                                              Wv, Wvc, (int)NW, Wo, Woc, (int)NW);

    // Q/K/V projections merged into one launch (grid.z selects which)
    gemm_qkv<<<dim3(EE/128, MM/128, 3), 256, 0, stream>>>(
        query, key_in, value, Wqc, Wkc, Wvc, bq, bk, bv, Qh, Kh, Vth,
        0.125f * LOG2E);

    flash_kernel<<<dim3(TT/128, BH), 512, 0, stream>>>(Qh, Kh, Vth, AO);

    gemm_out<<<dim3(EE/128, MM/128), 256, 0, stream>>>(AO, Woc, bo, (float*)d_out);
}

// Round 9
// 416.129 us; speedup vs baseline: 1.0532x; 1.0532x over previous
//
#include <hip/hip_runtime.h>
#include <hip/hip_bf16.h>
#include <cstdint>

// Problem constants
#define BB 4
#define TT 2048
#define EE 1024
#define HH 16
#define DD 64
#define BH (BB*HH)       // 64
#define MM (BB*TT)       // 8192 rows for projection GEMMs
#define KK 1024          // contraction dim for projections
#define KSTR 72          // flash K-tile LDS row stride (ushorts)
#define VSTR 136         // flash V-tile LDS row stride (ushorts)
#define LOG2E 1.44269504088896340736f

typedef __attribute__((ext_vector_type(8))) short short8;    // 8 x bf16
typedef __attribute__((ext_vector_type(4))) short short4_;   // 4 x bf16
typedef __attribute__((ext_vector_type(4))) float float4_;   // MFMA accumulator
typedef __attribute__((ext_vector_type(4))) ushort ushort4_;

__device__ __forceinline__ void gl_lds16(const void* g, void* l) {
    __builtin_amdgcn_global_load_lds(
        (const __attribute__((address_space(1))) void*)g,
        (__attribute__((address_space(3))) void*)l, 16, 0, 0);
}

__device__ __forceinline__ ushort f2bf(float v) {
    __hip_bfloat16 h = __float2bfloat16(v);
    return *(ushort*)&h;
}

// ---------------------------------------------------------------------------
// fp32 -> bf16 conversion (weights only). grid.y selects segment.
// ---------------------------------------------------------------------------
__global__ __launch_bounds__(256) void cvt_kernel(
    const float* __restrict__ s0, ushort* __restrict__ d0, int n0,
    const float* __restrict__ s1, ushort* __restrict__ d1, int n1,
    const float* __restrict__ s2, ushort* __restrict__ d2, int n2,
    const float* __restrict__ s3, ushort* __restrict__ d3, int n3)
{
    const float* s; ushort* d; int n;
    switch (blockIdx.y) {
        case 0: s = s0; d = d0; n = n0; break;
        case 1: s = s1; d = d1; n = n1; break;
        case 2: s = s2; d = d2; n = n2; break;
        default: s = s3; d = d3; n = n3; break;
    }
    int i = (blockIdx.x * 256 + threadIdx.x) * 4;
    if (i >= n) return;
    float4_ v = *(const float4_*)&s[i];
    ushort4_ o;
#pragma unroll
    for (int j = 0; j < 4; j++) o[j] = f2bf(v[j]);
    *(ushort4_*)&d[i] = o;
}

// ---------------------------------------------------------------------------
// MERGED Q/K/V projection GEMM.  1D grid + XCD-chunked bijective swizzle.
//
// Round-9 synthesis of R6/R7/R8 evidence:
//  * R6 (no swz): 150 us = 462 MB / 3.1 TB/s -> traffic-limited by 8x
//    replicated A panels across XCD L2s.  Swizzle (R7) fixes that (-6x).
//  * R7 (swz): 157 us with traffic gone -> serial-path-limited; the A
//    reg-staging chain (4 global loads -> 32 scalar cvts -> 4 ds_writes,
//    prefetch window < L2 latency) inflates every k-step.
//  * Fix both: A staged into LDS AS FP32 via global_load_lds (pure m97-form
//    staging for both operands: barrier -> issue 6 gl_lds -> barrier), with
//    fp32->bf16 conversion fused into the LDS->fragment read (off the
//    staging critical path, overlaps MFMA).  BK=32 (R8's BK=64 regressed:
//    3x bank conflicts).  LDS 24 KB -> 3 blocks/CU.
// C[n,e] = (sum_k A[n,k]*W[e,k] + bias[e])*scale
// z=0,1: scatter bf16 per-head [B*H, T, D];  z=2: transposed [B*H, D, T].
// ---------------------------------------------------------------------------
__global__ __launch_bounds__(256, 3) void gemm_qkv(
    const float* __restrict__ Aq, const float* __restrict__ Ak,
    const float* __restrict__ Av,
    const ushort* __restrict__ Wqc, const ushort* __restrict__ Wkc,
    const ushort* __restrict__ Wvc,
    const float* __restrict__ bq, const float* __restrict__ bk,
    const float* __restrict__ bv,
    ushort* __restrict__ Oq, ushort* __restrict__ Ok, ushort* __restrict__ Ov,
    float qscale)
{
    __shared__ __align__(16) float  Asf[128*32];   // fp32 A tile, 16 KB
    __shared__ __align__(16) ushort Bs [128*32];   // bf16 W tile,  8 KB

    // XCD-chunked bijective swizzle: 1536 blocks, 8 XCDs, 192/chunk.
    // All 8 col-blocks of a row-panel land on ONE XCD -> A panel L2-shared.
    const int bid = blockIdx.x;
    const int swz = (bid & 7) * 192 + (bid >> 3);
    const int z   = swz >> 9;          // 512 blocks per z
    const int rem = swz & 511;
    const int bx  = rem & 7;           // col-block (x fastest within chunk)
    const int by  = rem >> 3;          // row-block

    const float*  A    = (z == 0) ? Aq  : (z == 1) ? Ak  : Av;
    const ushort* W    = (z == 0) ? Wqc : (z == 1) ? Wkc : Wvc;
    const float*  bias = (z == 0) ? bq  : (z == 1) ? bk  : bv;
    ushort*       Cout = (z == 0) ? Oq  : (z == 1) ? Ok  : Ov;
    const float   scale = (z == 0) ? qscale : 1.0f;
    const bool    modeT = (z == 2);

    const int tid  = threadIdx.x;
    const int wave = tid >> 6;
    const int lane = tid & 63;
    const int l15  = lane & 15;
    const int quad = lane >> 4;
    const int wm   = wave & 1;   // row half
    const int wn   = wave >> 1;  // col half

    const long rowBase = (long)by * 128;
    const long colBase = (long)bx * 128;

    float4_ acc[4][4];
#pragma unroll
    for (int i = 0; i < 4; i++)
#pragma unroll
        for (int j = 0; j < 4; j++) acc[i][j] = float4_{0.f, 0.f, 0.f, 0.f};

    for (int k0 = 0; k0 < KK; k0 += 32) {
        __syncthreads();   // previous k-step's LDS reads done
        // A fp32: 128 rows x 32 k x 4B = 16 KB = 4 gl_lds/thread
        //   idx over 16B chunks: row = idx>>3, kseg = (idx&7)*4 floats
#pragma unroll
        for (int it = 0; it < 4; it++) {
            int idx = it * 256 + tid;
            int r = idx >> 3, c4 = (idx & 7) * 4;
            gl_lds16(A + (rowBase + r) * KK + k0 + c4, &Asf[idx * 4]);
        }
        // W bf16: 128 rows x 32 k x 2B = 8 KB = 2 gl_lds/thread
#pragma unroll
        for (int it = 0; it < 2; it++) {
            int idx = it * 256 + tid;
            int r = idx >> 2, c8 = (idx & 3) * 8;
            gl_lds16(W + (colBase + r) * KK + k0 + c8, &Bs[idx * 8]);
        }
        __syncthreads();

        // fragments: A read as fp32 + cvt (fused, overlaps MFMA), W as bf16
        short8 af[4], bf[4];
#pragma unroll
        for (int mt = 0; mt < 4; mt++) {
            const float* arow = &Asf[(wm*64 + mt*16 + l15) * 32 + quad*8];
            float4_ a0 = *(const float4_*)&arow[0];
            float4_ a1 = *(const float4_*)&arow[4];
#pragma unroll
            for (int j = 0; j < 4; j++) {
                af[mt][j]     = (short)f2bf(a0[j]);
                af[mt][j + 4] = (short)f2bf(a1[j]);
            }
        }
#pragma unroll
        for (int nt = 0; nt < 4; nt++)
            bf[nt] = *(const short8*)&Bs[(wn*64 + nt*16 + l15) * 32 + quad*8];
#pragma unroll
        for (int mt = 0; mt < 4; mt++)
#pragma unroll
            for (int nt = 0; nt < 4; nt++)
                acc[mt][nt] = __builtin_amdgcn_mfma_f32_16x16x32_bf16(
                    af[mt], bf[nt], acc[mt][nt], 0, 0, 0);
    }

    // Epilogue: C/D layout col = lane&15, row = quad*4 + reg
#pragma unroll
    for (int nt = 0; nt < 4; nt++) {
        const long col = colBase + wn*64 + nt*16 + l15;
        const float bvv = bias[col];
        const long h = col >> 6, d = col & (DD - 1);
#pragma unroll
        for (int mt = 0; mt < 4; mt++) {
            const long row0 = rowBase + wm*64 + mt*16 + quad*4;
            if (modeT) {
                const long b = row0 >> 11, t0 = row0 & (TT - 1);
                ushort4_ pk;
#pragma unroll
                for (int i = 0; i < 4; i++) pk[i] = f2bf((acc[mt][nt][i] + bvv) * scale);
                *(ushort4_*)&Cout[((b*HH + h)*DD + d)*TT + t0] = pk;
            } else {
#pragma unroll
                for (int i = 0; i < 4; i++) {
                    const long row = row0 + i;
                    const long b = row >> 11, t = row & (TT - 1);
                    Cout[(((b*HH + h) * TT) + t) * DD + d] =
                        f2bf((acc[mt][nt][i] + bvv) * scale);
                }
            }
        }
    }
}

// ---------------------------------------------------------------------------
// Output GEMM: m97-form (BK=32, gl_lds both operands) + XCD swizzle.
// C fp32 row-major [MM, EE] = (AO @ Wo^T + bo)
// ---------------------------------------------------------------------------
__global__ __launch_bounds__(256, 3) void gemm_out(
    const ushort* __restrict__ A, const ushort* __restrict__ W,
    const float* __restrict__ bias, float* __restrict__ Cout)
{
    __shared__ __align__(16) ushort As[128*32];
    __shared__ __align__(16) ushort Bs[128*32];

    const int bid = blockIdx.x;
    const int swz = (bid & 7) * 64 + (bid >> 3);   // 512 blocks, 64/chunk
    const int bx  = swz & 7;
    const int by  = swz >> 3;

    const int tid  = threadIdx.x;
    const int wave = tid >> 6;
    const int lane = tid & 63;
    const int l15  = lane & 15;
    const int quad = lane >> 4;
    const int wm   = wave & 1;
    const int wn   = wave >> 1;

    const long rowBase = (long)by * 128;
    const long colBase = (long)bx * 128;

    float4_ acc[4][4];
#pragma unroll
    for (int i = 0; i < 4; i++)
#pragma unroll
        for (int j = 0; j < 4; j++) acc[i][j] = float4_{0.f, 0.f, 0.f, 0.f};

    for (int k0 = 0; k0 < KK; k0 += 32) {
        __syncthreads();
#pragma unroll
        for (int it = 0; it < 2; it++) {
            int idx = it * 256 + tid;
            int r   = idx >> 2;
            int c8  = (idx & 3) * 8;
            gl_lds16(A + (rowBase + r) * KK + k0 + c8, &As[idx * 8]);
            gl_lds16(W + (colBase + r) * KK + k0 + c8, &Bs[idx * 8]);
        }
        __syncthreads();

        short8 af[4], bf[4];
#pragma unroll
        for (int mt = 0; mt < 4; mt++)
            af[mt] = *(const short8*)&As[(wm*64 + mt*16 + l15) * 32 + quad*8];
#pragma unroll
        for (int nt = 0; nt < 4; nt++)
            bf[nt] = *(const short8*)&Bs[(wn*64 + nt*16 + l15) * 32 + quad*8];
#pragma unroll
        for (int mt = 0; mt < 4; mt++)
#pragma unroll
            for (int nt = 0; nt < 4; nt++)
                acc[mt][nt] = __builtin_amdgcn_mfma_f32_16x16x32_bf16(
                    af[mt], bf[nt], acc[mt][nt], 0, 0, 0);
    }

#pragma unroll
    for (int nt = 0; nt < 4; nt++) {
        const long col = colBase + wn*64 + nt*16 + l15;
        const float bv = bias[col];
#pragma unroll
        for (int mt = 0; mt < 4; mt++) {
            const long row0 = rowBase + wm*64 + mt*16 + quad*4;
#pragma unroll
            for (int i = 0; i < 4; i++)
                Cout[(row0 + i) * EE + col] = acc[mt][nt][i] + bv;
        }
    }
}

// ---------------------------------------------------------------------------
// Flash attention (causal). Q,K: [B*H, T, D] bf16; Vt: [B*H, D, T] bf16;
// AO: [B, T, E] bf16.  Q pre-scaled by 0.125*log2(e) -> softmax via exp2.
// (Unchanged: operand-swapped S^T = mfma(K,Q), scalar softmax state, P in
// registers, LDS 35.8 KB, launch_bounds (512,4).)
// ---------------------------------------------------------------------------
__global__ __launch_bounds__(512, 4) void flash_kernel(
    const ushort* __restrict__ Qh, const ushort* __restrict__ Kh,
    const ushort* __restrict__ Vt, ushort* __restrict__ AO)
{
    __shared__ __align__(16) ushort Ks[128*KSTR];    // [key][d]     18.4 KB
    __shared__ __align__(16) ushort Vs[64*VSTR];     // [d][key]     17.4 KB

    const int qt  = (TT/128 - 1) - blockIdx.x;  // heavy tiles dispatch first
    const int bh  = blockIdx.y;                 // b*H + h
    const int tid = threadIdx.x;
    const int wave = tid >> 6, lane = tid & 63;
    const int l15 = lane & 15, quad = lane >> 4;

    const ushort* Qb = Qh + (long)bh * TT * DD;
    const ushort* Kb = Kh + (long)bh * TT * DD;
    const ushort* Vb = Vt + (long)bh * DD * TT;

    // This lane's q-row (B-fragment of swapped QK^T; also the output t)
    const int qrow = qt*128 + wave*16 + l15;
    short8 aq0 = *(const short8*)&Qb[(long)qrow * DD + quad*8];
    short8 aq1 = *(const short8*)&Qb[(long)qrow * DD + 32 + quad*8];

    // O^T accumulator: o[nt][i] = O[q=qrow][d = nt*16 + quad*4 + i]
    float4_ o[4];
#pragma unroll
    for (int nt = 0; nt < 4; nt++) o[nt] = float4_{0.f, 0.f, 0.f, 0.f};
    float m_run = -INFINITY, l_run = 0.0f;      // scalar per lane (one q-row)

    const int nkt = qt + 1;                    // number of 128-key tiles

    // prefetch tile 0 into registers (K: 128x64, V^T: 64x128)
    short8 kreg[2], vreg[2];
#pragma unroll
    for (int it = 0; it < 2; it++) {
        int c = it * 512 + tid;                    // 0..1023
        int kk = c >> 3, ks = c & 7;               // K: key, 16B seg
        kreg[it] = *(const short8*)&Kb[(long)kk * DD + ks*8];
        int dd = c >> 4, vs = c & 15;              // V: d, 16B seg
        vreg[it] = *(const short8*)&Vb[(long)dd * TT + vs*8];
    }

    for (int kt = 0; kt < nkt; kt++) {
        __syncthreads();   // previous tile's LDS reads done
#pragma unroll
        for (int it = 0; it < 2; it++) {
            int c = it * 512 + tid;
            int kk = c >> 3, ks = c & 7;
            *(short8*)&Ks[kk*KSTR + ks*8] = kreg[it];
            int dd = c >> 4, vs = c & 15;
            *(short8*)&Vs[dd*VSTR + vs*8] = vreg[it];
        }
        __syncthreads();

        // prefetch next tile (latency overlaps all compute below)
        if (kt + 1 < nkt) {
            const long koff = (long)(kt+1) * 128;
#pragma unroll
            for (int it = 0; it < 2; it++) {
                int c = it * 512 + tid;
                int kk = c >> 3, ks = c & 7;
                kreg[it] = *(const short8*)&Kb[(koff + kk) * DD + ks*8];
                int dd = c >> 4, vs = c & 15;
                vreg[it] = *(const short8*)&Vb[(long)dd * TT + koff + vs*8];
            }
        }

        // S^T = mfma(K, Q): col = q = l15, row = key = quad*4 + i
        float4_ s[8];
        __builtin_amdgcn_s_setprio(1);
#pragma unroll
        for (int nt = 0; nt < 8; nt++) {
            short8 bk0 = *(const short8*)&Ks[(nt*16 + l15) * KSTR + quad*8];
            short8 bk1 = *(const short8*)&Ks[(nt*16 + l15) * KSTR + 32 + quad*8];
            float4_ acc = float4_{0.f, 0.f, 0.f, 0.f};
            acc = __builtin_amdgcn_mfma_f32_16x16x32_bf16(bk0, aq0, acc, 0,0,0);
            acc = __builtin_amdgcn_mfma_f32_16x16x32_bf16(bk1, aq1, acc, 0,0,0);
            s[nt] = acc;
        }
        __builtin_amdgcn_s_setprio(0);

        if (kt == nkt - 1) {   // only the diagonal tile crosses the mask
#pragma unroll
            for (int nt = 0; nt < 8; nt++) {
#pragma unroll
                for (int i = 0; i < 4; i++) {
                    const int key = kt*128 + nt*16 + quad*4 + i;
                    if (key > qrow) s[nt][i] = -INFINITY;
                }
            }
        }

        // row max: in-register tree over this lane's 32 keys + cross-quad shfl
        float t8[8];
#pragma unroll
        for (int nt = 0; nt < 8; nt++)
            t8[nt] = fmaxf(fmaxf(s[nt][0], s[nt][1]), fmaxf(s[nt][2], s[nt][3]));
        float pm = fmaxf(fmaxf(fmaxf(t8[0], t8[1]), fmaxf(t8[2], t8[3])),
                         fmaxf(fmaxf(t8[4], t8[5]), fmaxf(t8[6], t8[7])));
        pm = fmaxf(pm, __shfl_xor(pm, 16));
        pm = fmaxf(pm, __shfl_xor(pm, 32));

        // T13 defer-max: skip rescale if max grew by < 8 (log2 domain, <=2^8)
        if (!__all(pm <= m_run + 8.0f)) {
            const float mnew = fmaxf(m_run, pm);
            const float alpha = exp2f(m_run - mnew);   // 0 on first tile
            m_run = mnew;
            l_run *= alpha;
#pragma unroll
            for (int nt = 0; nt < 4; nt++)
#pragma unroll
                for (int i = 0; i < 4; i++) o[nt][i] *= alpha;
        }

        // P = exp2(S - m): accumulate row sum and pack to bf16 immediately
        float rs0 = 0.f, rs1 = 0.f, rs2 = 0.f, rs3 = 0.f;
        short8 pb[4];
#pragma unroll
        for (int c = 0; c < 4; c++) {
#pragma unroll
            for (int half = 0; half < 2; half++) {
                const int nt = 2*c + half;
                const float p0 = exp2f(s[nt][0] - m_run);  // masked -> 0
                const float p1 = exp2f(s[nt][1] - m_run);
                const float p2 = exp2f(s[nt][2] - m_run);
                const float p3 = exp2f(s[nt][3] - m_run);
                rs0 += p0; rs1 += p1; rs2 += p2; rs3 += p3;
                pb[c][half*4 + 0] = (short)f2bf(p0);
                pb[c][half*4 + 1] = (short)f2bf(p1);
                pb[c][half*4 + 2] = (short)f2bf(p2);
                pb[c][half*4 + 3] = (short)f2bf(p3);
            }
        }
        float rs = (rs0 + rs1) + (rs2 + rs3);
        rs += __shfl_xor(rs, 16);
        rs += __shfl_xor(rs, 32);
        l_run += rs;

        // O^T += V^T @ P^T, P straight from registers.
        // k-slot (quad,j) -> key (2c + (j>>2))*16 + quad*4 + (j&3); V reads
        // use the same mapping: two b64 loads per output tile.
        __builtin_amdgcn_s_setprio(1);
#pragma unroll
        for (int c = 0; c < 4; c++) {
            const short8 bp = pb[c];
#pragma unroll
            for (int nt = 0; nt < 4; nt++) {
                const ushort* vrow = &Vs[(nt*16 + l15) * VSTR];
                short4_ lo = *(const short4_*)&vrow[(2*c    )*16 + quad*4];
                short4_ hi = *(const short4_*)&vrow[(2*c + 1)*16 + quad*4];
                short8 av;
                av[0]=lo[0]; av[1]=lo[1]; av[2]=lo[2]; av[3]=lo[3];
                av[4]=hi[0]; av[5]=hi[1]; av[6]=hi[2]; av[7]=hi[3];
                o[nt] = __builtin_amdgcn_mfma_f32_16x16x32_bf16(av, bp, o[nt], 0,0,0);
            }
        }
        __builtin_amdgcn_s_setprio(0);
    }

    // epilogue: AO[b, t=qrow, h*64 + d] = o / l ; d = nt*16 + quad*4 + i
    const int h = bh & (HH - 1);
    const int b = bh >> 4;
    const float inv = 1.0f / l_run;
    const long rowOff = ((long)(b*TT + qrow)) * EE + h*64;
#pragma unroll
    for (int nt = 0; nt < 4; nt++) {
        ushort4_ pk;
#pragma unroll
        for (int i = 0; i < 4; i++) pk[i] = f2bf(o[nt][i] * inv);
        *(ushort4_*)&AO[rowOff + nt*16 + quad*4] = pk;
    }
}

// ---------------------------------------------------------------------------
extern "C" void kernel_launch(void* const* d_in, const int* in_sizes, int n_in,
                              void* d_out, int out_size, void* d_ws, size_t ws_size,
                              hipStream_t stream)
{
    const float* query  = (const float*)d_in[0];
    const float* key_in = (const float*)d_in[1];
    const float* value  = (const float*)d_in[2];
    // d_in[3] = mask (int32 tril) — causal is hard-coded in flash_kernel
    const float* Wq = (const float*)d_in[4];
    const float* bq = (const float*)d_in[5];
    const float* Wk = (const float*)d_in[6];
    const float* bk = (const float*)d_in[7];
    const float* Wv = (const float*)d_in[8];
    const float* bv = (const float*)d_in[9];
    const float* Wo = (const float*)d_in[10];
    const float* bo = (const float*)d_in[11];

    ushort* ws = (ushort*)d_ws;
    const size_t NIN = (size_t)MM * KK;        // 8,388,608 elems
    const size_t NW  = (size_t)EE * KK;        // 1,048,576 elems (weights)
    ushort* Wqc = ws;                          // 2 MB each
    ushort* Wkc = Wqc + NW;
    ushort* Wvc = Wkc + NW;
    ushort* Woc = Wvc + NW;
    ushort* Qh  = Woc + NW;                    // 16 MB  [bh][t][d], pre-scaled
    ushort* Kh  = Qh + NIN;                    // 16 MB  [bh][t][d]
    ushort* Vth = Kh + NIN;                    // 16 MB  [bh][d][t]
    ushort* AO  = Vth + NIN;                   // 16 MB  [b][t][e]  (total 72 MB)

    const dim3 cvtW_grid(NW/1024, 4);

    // weights -> bf16 (one batched launch)
    cvt_kernel<<<cvtW_grid, 256, 0, stream>>>(Wq, Wqc, (int)NW, Wk, Wkc, (int)NW,
                                              Wv, Wvc, (int)NW, Wo, Woc, (int)NW);

    // Q/K/V projections merged, 1D grid with XCD-chunked swizzle
    gemm_qkv<<<dim3(3 * (EE/128) * (MM/128)), 256, 0, stream>>>(
        query, key_in, value, Wqc, Wkc, Wvc, bq, bk, bv, Qh, Kh, Vth,
        0.125f * LOG2E);

    flash_kernel<<<dim3(TT/128, BH), 512, 0, stream>>>(Qh, Kh, Vth, AO);

    gemm_out<<<dim3((EE/128) * (MM/128)), 256, 0, stream>>>(AO, Woc, bo, (float*)d_out);
}

// Round 10
// 364.692 us; speedup vs baseline: 1.2018x; 1.1410x over previous
//
#include <hip/hip_runtime.h>
#include <hip/hip_bf16.h>
#include <cstdint>

// Problem constants
#define BB 4
#define TT 2048
#define EE 1024
#define HH 16
#define DD 64
#define BH (BB*HH)       // 64
#define MM (BB*TT)       // 8192 rows for projection GEMMs
#define KK 1024          // contraction dim for projections
#define KSTR 72          // flash K-tile LDS row stride (ushorts)
#define VSTR 136         // flash V-tile LDS row stride (ushorts)
#define LOG2E 1.44269504088896340736f

typedef __attribute__((ext_vector_type(8))) short short8;    // 8 x bf16
typedef __attribute__((ext_vector_type(4))) short short4_;   // 4 x bf16
typedef __attribute__((ext_vector_type(4))) float float4_;   // MFMA accumulator
typedef __attribute__((ext_vector_type(4))) ushort ushort4_;

__device__ __forceinline__ void gl_lds16(const void* g, void* l) {
    __builtin_amdgcn_global_load_lds(
        (const __attribute__((address_space(1))) void*)g,
        (__attribute__((address_space(3))) void*)l, 16, 0, 0);
}

__device__ __forceinline__ ushort f2bf(float v) {
    __hip_bfloat16 h = __float2bfloat16(v);
    return *(ushort*)&h;
}

// ---------------------------------------------------------------------------
// fp32 -> bf16 conversion (weights only). grid.y selects segment.
// ---------------------------------------------------------------------------
__global__ __launch_bounds__(256) void cvt_kernel(
    const float* __restrict__ s0, ushort* __restrict__ d0, int n0,
    const float* __restrict__ s1, ushort* __restrict__ d1, int n1,
    const float* __restrict__ s2, ushort* __restrict__ d2, int n2,
    const float* __restrict__ s3, ushort* __restrict__ d3, int n3)
{
    const float* s; ushort* d; int n;
    switch (blockIdx.y) {
        case 0: s = s0; d = d0; n = n0; break;
        case 1: s = s1; d = d1; n = n1; break;
        case 2: s = s2; d = d2; n = n2; break;
        default: s = s3; d = d3; n = n3; break;
    }
    int i = (blockIdx.x * 256 + threadIdx.x) * 4;
    if (i >= n) return;
    float4_ v = *(const float4_*)&s[i];
    ushort4_ o;
#pragma unroll
    for (int j = 0; j < 4; j++) o[j] = f2bf(v[j]);
    *(ushort4_*)&d[i] = o;
}

// ---------------------------------------------------------------------------
// MERGED Q/K/V projection GEMM.  1D grid + XCD-chunked bijective swizzle.
// (R9 form, unchanged: A staged into LDS as FP32 via global_load_lds with
// fp32->bf16 fused into the LDS->fragment read; W via global_load_lds;
// BK=32; 24 KB LDS -> 3 blocks/CU; swizzle keeps A panels L2-shared.)
// C[n,e] = (sum_k A[n,k]*W[e,k] + bias[e])*scale
// z=0,1: scatter bf16 per-head [B*H, T, D];  z=2: transposed [B*H, D, T].
// ---------------------------------------------------------------------------
__global__ __launch_bounds__(256, 3) void gemm_qkv(
    const float* __restrict__ Aq, const float* __restrict__ Ak,
    const float* __restrict__ Av,
    const ushort* __restrict__ Wqc, const ushort* __restrict__ Wkc,
    const ushort* __restrict__ Wvc,
    const float* __restrict__ bq, const float* __restrict__ bk,
    const float* __restrict__ bv,
    ushort* __restrict__ Oq, ushort* __restrict__ Ok, ushort* __restrict__ Ov,
    float qscale)
{
    __shared__ __align__(16) float  Asf[128*32];   // fp32 A tile, 16 KB
    __shared__ __align__(16) ushort Bs [128*32];   // bf16 W tile,  8 KB

    const int bid = blockIdx.x;
    const int swz = (bid & 7) * 192 + (bid >> 3);
    const int z   = swz >> 9;          // 512 blocks per z
    const int rem = swz & 511;
    const int bx  = rem & 7;           // col-block (x fastest within chunk)
    const int by  = rem >> 3;          // row-block

    const float*  A    = (z == 0) ? Aq  : (z == 1) ? Ak  : Av;
    const ushort* W    = (z == 0) ? Wqc : (z == 1) ? Wkc : Wvc;
    const float*  bias = (z == 0) ? bq  : (z == 1) ? bk  : bv;
    ushort*       Cout = (z == 0) ? Oq  : (z == 1) ? Ok  : Ov;
    const float   scale = (z == 0) ? qscale : 1.0f;
    const bool    modeT = (z == 2);

    const int tid  = threadIdx.x;
    const int wave = tid >> 6;
    const int lane = tid & 63;
    const int l15  = lane & 15;
    const int quad = lane >> 4;
    const int wm   = wave & 1;   // row half
    const int wn   = wave >> 1;  // col half

    const long rowBase = (long)by * 128;
    const long colBase = (long)bx * 128;

    float4_ acc[4][4];
#pragma unroll
    for (int i = 0; i < 4; i++)
#pragma unroll
        for (int j = 0; j < 4; j++) acc[i][j] = float4_{0.f, 0.f, 0.f, 0.f};

    for (int k0 = 0; k0 < KK; k0 += 32) {
        __syncthreads();   // previous k-step's LDS reads done
#pragma unroll
        for (int it = 0; it < 4; it++) {
            int idx = it * 256 + tid;
            int r = idx >> 3, c4 = (idx & 7) * 4;
            gl_lds16(A + (rowBase + r) * KK + k0 + c4, &Asf[idx * 4]);
        }
#pragma unroll
        for (int it = 0; it < 2; it++) {
            int idx = it * 256 + tid;
            int r = idx >> 2, c8 = (idx & 3) * 8;
            gl_lds16(W + (colBase + r) * KK + k0 + c8, &Bs[idx * 8]);
        }
        __syncthreads();

        short8 af[4], bf[4];
#pragma unroll
        for (int mt = 0; mt < 4; mt++) {
            const float* arow = &Asf[(wm*64 + mt*16 + l15) * 32 + quad*8];
            float4_ a0 = *(const float4_*)&arow[0];
            float4_ a1 = *(const float4_*)&arow[4];
#pragma unroll
            for (int j = 0; j < 4; j++) {
                af[mt][j]     = (short)f2bf(a0[j]);
                af[mt][j + 4] = (short)f2bf(a1[j]);
            }
        }
#pragma unroll
        for (int nt = 0; nt < 4; nt++)
            bf[nt] = *(const short8*)&Bs[(wn*64 + nt*16 + l15) * 32 + quad*8];
#pragma unroll
        for (int mt = 0; mt < 4; mt++)
#pragma unroll
            for (int nt = 0; nt < 4; nt++)
                acc[mt][nt] = __builtin_amdgcn_mfma_f32_16x16x32_bf16(
                    af[mt], bf[nt], acc[mt][nt], 0, 0, 0);
    }

    // Epilogue: C/D layout col = lane&15, row = quad*4 + reg
#pragma unroll
    for (int nt = 0; nt < 4; nt++) {
        const long col = colBase + wn*64 + nt*16 + l15;
        const float bvv = bias[col];
        const long h = col >> 6, d = col & (DD - 1);
#pragma unroll
        for (int mt = 0; mt < 4; mt++) {
            const long row0 = rowBase + wm*64 + mt*16 + quad*4;
            if (modeT) {
                const long b = row0 >> 11, t0 = row0 & (TT - 1);
                ushort4_ pk;
#pragma unroll
                for (int i = 0; i < 4; i++) pk[i] = f2bf((acc[mt][nt][i] + bvv) * scale);
                *(ushort4_*)&Cout[((b*HH + h)*DD + d)*TT + t0] = pk;
            } else {
#pragma unroll
                for (int i = 0; i < 4; i++) {
                    const long row = row0 + i;
                    const long b = row >> 11, t = row & (TT - 1);
                    Cout[(((b*HH + h) * TT) + t) * DD + d] =
                        f2bf((acc[mt][nt][i] + bvv) * scale);
                }
            }
        }
    }
}

// ---------------------------------------------------------------------------
// Output GEMM: m97-form (BK=32, gl_lds both operands) + XCD swizzle.
// C fp32 row-major [MM, EE] = (AO @ Wo^T + bo)
// ---------------------------------------------------------------------------
__global__ __launch_bounds__(256, 3) void gemm_out(
    const ushort* __restrict__ A, const ushort* __restrict__ W,
    const float* __restrict__ bias, float* __restrict__ Cout)
{
    __shared__ __align__(16) ushort As[128*32];
    __shared__ __align__(16) ushort Bs[128*32];

    const int bid = blockIdx.x;
    const int swz = (bid & 7) * 64 + (bid >> 3);   // 512 blocks, 64/chunk
    const int bx  = swz & 7;
    const int by  = swz >> 3;

    const int tid  = threadIdx.x;
    const int wave = tid >> 6;
    const int lane = tid & 63;
    const int l15  = lane & 15;
    const int quad = lane >> 4;
    const int wm   = wave & 1;
    const int wn   = wave >> 1;

    const long rowBase = (long)by * 128;
    const long colBase = (long)bx * 128;

    float4_ acc[4][4];
#pragma unroll
    for (int i = 0; i < 4; i++)
#pragma unroll
        for (int j = 0; j < 4; j++) acc[i][j] = float4_{0.f, 0.f, 0.f, 0.f};

    for (int k0 = 0; k0 < KK; k0 += 32) {
        __syncthreads();
#pragma unroll
        for (int it = 0; it < 2; it++) {
            int idx = it * 256 + tid;
            int r   = idx >> 2;
            int c8  = (idx & 3) * 8;
            gl_lds16(A + (rowBase + r) * KK + k0 + c8, &As[idx * 8]);
            gl_lds16(W + (colBase + r) * KK + k0 + c8, &Bs[idx * 8]);
        }
        __syncthreads();

        short8 af[4], bf[4];
#pragma unroll
        for (int mt = 0; mt < 4; mt++)
            af[mt] = *(const short8*)&As[(wm*64 + mt*16 + l15) * 32 + quad*8];
#pragma unroll
        for (int nt = 0; nt < 4; nt++)
            bf[nt] = *(const short8*)&Bs[(wn*64 + nt*16 + l15) * 32 + quad*8];
#pragma unroll
        for (int mt = 0; mt < 4; mt++)
#pragma unroll
            for (int nt = 0; nt < 4; nt++)
                acc[mt][nt] = __builtin_amdgcn_mfma_f32_16x16x32_bf16(
                    af[mt], bf[nt], acc[mt][nt], 0, 0, 0);
    }

#pragma unroll
    for (int nt = 0; nt < 4; nt++) {
        const long col = colBase + wn*64 + nt*16 + l15;
        const float bv = bias[col];
#pragma unroll
        for (int mt = 0; mt < 4; mt++) {
            const long row0 = rowBase + wm*64 + mt*16 + quad*4;
#pragma unroll
            for (int i = 0; i < 4; i++)
                Cout[(row0 + i) * EE + col] = acc[mt][nt][i] + bv;
        }
    }
}

// ---------------------------------------------------------------------------
// Flash attention (causal). Q,K: [B*H, T, D] bf16; Vt: [B*H, D, T] bf16;
// AO: [B, T, E] bf16.  Q pre-scaled by 0.125*log2(e) -> softmax via exp2.
//
// Round-10 changes (flash was tail/imbalance-bound: 1024 blocks = exactly
// device residency, work skewed 1..16 tiles -> light blocks finish and their
// slots idle; OccupancyPercent 22% vs 100% nominal):
//  1. CAUSAL PAIR-BALANCING: each block serially processes q-tile (15-p)
//     then q-tile p -> every block does exactly 17 tiles.  Grid 8x64 = 512
//     blocks = 2/CU, fully resident and uniformly busy to the end.
//  2. DOUBLE-BUFFERED K/V LDS (71.7 KB, fits 2 blocks/CU exactly): per tile
//     {issue prefetch -> compute buf[cur] -> ds_write buf[cur^1] -> barrier}
//     -> ONE barrier per tile instead of two.
// Inner math unchanged (operand-swapped S^T = mfma(K,Q), scalar softmax
// state, P in registers).
// ---------------------------------------------------------------------------
__global__ __launch_bounds__(512, 4) void flash_kernel(
    const ushort* __restrict__ Qh, const ushort* __restrict__ Kh,
    const ushort* __restrict__ Vt, ushort* __restrict__ AO)
{
    __shared__ __align__(16) ushort Ks[2][128*KSTR];   // [buf][key][d]  36.9 KB
    __shared__ __align__(16) ushort Vs[2][64*VSTR];    // [buf][d][key]  34.8 KB

    const int p   = blockIdx.x;                 // pair index 0..7
    const int bh  = blockIdx.y;                 // b*H + h
    const int tid = threadIdx.x;
    const int wave = tid >> 6, lane = tid & 63;
    const int l15 = lane & 15, quad = lane >> 4;

    const ushort* Qb = Qh + (long)bh * TT * DD;
    const ushort* Kb = Kh + (long)bh * TT * DD;
    const ushort* Vb = Vt + (long)bh * DD * TT;
    const int h = bh & (HH - 1);
    const int b = bh >> 4;

    // staging geometry (constant per thread)
    int kks[2], kss[2], dds[2], vss[2];
#pragma unroll
    for (int it = 0; it < 2; it++) {
        int c = it * 512 + tid;                 // 0..1023
        kks[it] = c >> 3; kss[it] = c & 7;      // K: key, 16B seg
        dds[it] = c >> 4; vss[it] = c & 15;     // V: d, 16B seg
    }

#pragma unroll
    for (int seg = 0; seg < 2; seg++) {
        const int qt  = (seg == 0) ? (15 - p) : p;   // heavy first
        const int nkt = qt + 1;

        // this segment's q-row (B-frag of swapped QK^T; also the output t)
        const int qrow = qt*128 + wave*16 + l15;
        short8 aq0 = *(const short8*)&Qb[(long)qrow * DD + quad*8];
        short8 aq1 = *(const short8*)&Qb[(long)qrow * DD + 32 + quad*8];

        float4_ o[4];
#pragma unroll
        for (int nt = 0; nt < 4; nt++) o[nt] = float4_{0.f, 0.f, 0.f, 0.f};
        float m_run = -INFINITY, l_run = 0.0f;

        // stage tile 0 -> buf 0
        short8 kreg[2], vreg[2];
#pragma unroll
        for (int it = 0; it < 2; it++) {
            kreg[it] = *(const short8*)&Kb[(long)kks[it] * DD + kss[it]*8];
            vreg[it] = *(const short8*)&Vb[(long)dds[it] * TT + vss[it]*8];
        }
        __syncthreads();   // all waves done reading every buffer (prev seg)
#pragma unroll
        for (int it = 0; it < 2; it++) {
            *(short8*)&Ks[0][kks[it]*KSTR + kss[it]*8] = kreg[it];
            *(short8*)&Vs[0][dds[it]*VSTR + vss[it]*8] = vreg[it];
        }
        __syncthreads();
        int cur = 0;

        for (int kt = 0; kt < nkt; kt++) {
            // prefetch next tile into regs (latency hides under compute)
            if (kt + 1 < nkt) {
                const long koff = (long)(kt+1) * 128;
#pragma unroll
                for (int it = 0; it < 2; it++) {
                    kreg[it] = *(const short8*)&Kb[(koff + kks[it]) * DD + kss[it]*8];
                    vreg[it] = *(const short8*)&Vb[(long)dds[it] * TT + koff + vss[it]*8];
                }
            }
            const ushort* ksb = &Ks[cur][0];
            const ushort* vsb = &Vs[cur][0];

            // S^T = mfma(K, Q): col = q = l15, row = key = quad*4 + i
            float4_ s[8];
            __builtin_amdgcn_s_setprio(1);
#pragma unroll
            for (int nt = 0; nt < 8; nt++) {
                short8 bk0 = *(const short8*)&ksb[(nt*16 + l15) * KSTR + quad*8];
                short8 bk1 = *(const short8*)&ksb[(nt*16 + l15) * KSTR + 32 + quad*8];
                float4_ acc = float4_{0.f, 0.f, 0.f, 0.f};
                acc = __builtin_amdgcn_mfma_f32_16x16x32_bf16(bk0, aq0, acc, 0,0,0);
                acc = __builtin_amdgcn_mfma_f32_16x16x32_bf16(bk1, aq1, acc, 0,0,0);
                s[nt] = acc;
            }
            __builtin_amdgcn_s_setprio(0);

            if (kt == nkt - 1) {   // only the diagonal tile crosses the mask
#pragma unroll
                for (int nt = 0; nt < 8; nt++) {
#pragma unroll
                    for (int i = 0; i < 4; i++) {
                        const int key = kt*128 + nt*16 + quad*4 + i;
                        if (key > qrow) s[nt][i] = -INFINITY;
                    }
                }
            }

            // row max: register tree over 32 keys + 2 cross-quad shfls
            float t8[8];
#pragma unroll
            for (int nt = 0; nt < 8; nt++)
                t8[nt] = fmaxf(fmaxf(s[nt][0], s[nt][1]), fmaxf(s[nt][2], s[nt][3]));
            float pm = fmaxf(fmaxf(fmaxf(t8[0], t8[1]), fmaxf(t8[2], t8[3])),
                             fmaxf(fmaxf(t8[4], t8[5]), fmaxf(t8[6], t8[7])));
            pm = fmaxf(pm, __shfl_xor(pm, 16));
            pm = fmaxf(pm, __shfl_xor(pm, 32));

            // T13 defer-max
            if (!__all(pm <= m_run + 8.0f)) {
                const float mnew = fmaxf(m_run, pm);
                const float alpha = exp2f(m_run - mnew);
                m_run = mnew;
                l_run *= alpha;
#pragma unroll
                for (int nt = 0; nt < 4; nt++)
#pragma unroll
                    for (int i = 0; i < 4; i++) o[nt][i] *= alpha;
            }

            // P = exp2(S - m): row sum + immediate bf16 pack
            float rs0 = 0.f, rs1 = 0.f, rs2 = 0.f, rs3 = 0.f;
            short8 pb[4];
#pragma unroll
            for (int c = 0; c < 4; c++) {
#pragma unroll
                for (int half = 0; half < 2; half++) {
                    const int nt = 2*c + half;
                    const float p0 = exp2f(s[nt][0] - m_run);
                    const float p1 = exp2f(s[nt][1] - m_run);
                    const float p2 = exp2f(s[nt][2] - m_run);
                    const float p3 = exp2f(s[nt][3] - m_run);
                    rs0 += p0; rs1 += p1; rs2 += p2; rs3 += p3;
                    pb[c][half*4 + 0] = (short)f2bf(p0);
                    pb[c][half*4 + 1] = (short)f2bf(p1);
                    pb[c][half*4 + 2] = (short)f2bf(p2);
                    pb[c][half*4 + 3] = (short)f2bf(p3);
                }
            }
            float rs = (rs0 + rs1) + (rs2 + rs3);
            rs += __shfl_xor(rs, 16);
            rs += __shfl_xor(rs, 32);
            l_run += rs;

            // O^T += V^T @ P^T, P from registers.
            __builtin_amdgcn_s_setprio(1);
#pragma unroll
            for (int c = 0; c < 4; c++) {
                const short8 bp = pb[c];
#pragma unroll
                for (int nt = 0; nt < 4; nt++) {
                    const ushort* vrow = &vsb[(nt*16 + l15) * VSTR];
                    short4_ lo = *(const short4_*)&vrow[(2*c    )*16 + quad*4];
                    short4_ hi = *(const short4_*)&vrow[(2*c + 1)*16 + quad*4];
                    short8 av;
                    av[0]=lo[0]; av[1]=lo[1]; av[2]=lo[2]; av[3]=lo[3];
                    av[4]=hi[0]; av[5]=hi[1]; av[6]=hi[2]; av[7]=hi[3];
                    o[nt] = __builtin_amdgcn_mfma_f32_16x16x32_bf16(av, bp, o[nt], 0,0,0);
                }
            }
            __builtin_amdgcn_s_setprio(0);

            // publish next tile into the other buffer; single barrier per tile
            if (kt + 1 < nkt) {
#pragma unroll
                for (int it = 0; it < 2; it++) {
                    *(short8*)&Ks[cur^1][kks[it]*KSTR + kss[it]*8] = kreg[it];
                    *(short8*)&Vs[cur^1][dds[it]*VSTR + vss[it]*8] = vreg[it];
                }
                __syncthreads();
                cur ^= 1;
            }
        }

        // epilogue: AO[b, t=qrow, h*64 + d] = o / l
        const float inv = 1.0f / l_run;
        const long rowOff = ((long)(b*TT + qrow)) * EE + h*64;
#pragma unroll
        for (int nt = 0; nt < 4; nt++) {
            ushort4_ pk;
#pragma unroll
            for (int i = 0; i < 4; i++) pk[i] = f2bf(o[nt][i] * inv);
            *(ushort4_*)&AO[rowOff + nt*16 + quad*4] = pk;
        }
    }
}

// ---------------------------------------------------------------------------
extern "C" void kernel_launch(void* const* d_in, const int* in_sizes, int n_in,
                              void* d_out, int out_size, void* d_ws, size_t ws_size,
                              hipStream_t stream)
{
    const float* query  = (const float*)d_in[0];
    const float* key_in = (const float*)d_in[1];
    const float* value  = (const float*)d_in[2];
    // d_in[3] = mask (int32 tril) — causal is hard-coded in flash_kernel
    const float* Wq = (const float*)d_in[4];
    const float* bq = (const float*)d_in[5];
    const float* Wk = (const float*)d_in[6];
    const float* bk = (const float*)d_in[7];
    const float* Wv = (const float*)d_in[8];
    const float* bv = (const float*)d_in[9];
    const float* Wo = (const float*)d_in[10];
    const float* bo = (const float*)d_in[11];

    ushort* ws = (ushort*)d_ws;
    const size_t NIN = (size_t)MM * KK;        // 8,388,608 elems
    const size_t NW  = (size_t)EE * KK;        // 1,048,576 elems (weights)
    ushort* Wqc = ws;                          // 2 MB each
    ushort* Wkc = Wqc + NW;
    ushort* Wvc = Wkc + NW;
    ushort* Woc = Wvc + NW;
    ushort* Qh  = Woc + NW;                    // 16 MB  [bh][t][d], pre-scaled
    ushort* Kh  = Qh + NIN;                    // 16 MB  [bh][t][d]
    ushort* Vth = Kh + NIN;                    // 16 MB  [bh][d][t]
    ushort* AO  = Vth + NIN;                   // 16 MB  [b][t][e]  (total 72 MB)

    const dim3 cvtW_grid(NW/1024, 4);

    // weights -> bf16 (one batched launch)
    cvt_kernel<<<cvtW_grid, 256, 0, stream>>>(Wq, Wqc, (int)NW, Wk, Wkc, (int)NW,
                                              Wv, Wvc, (int)NW, Wo, Woc, (int)NW);

    // Q/K/V projections merged, 1D grid with XCD-chunked swizzle
    gemm_qkv<<<dim3(3 * (EE/128) * (MM/128)), 256, 0, stream>>>(
        query, key_in, value, Wqc, Wkc, Wvc, bq, bk, bv, Qh, Kh, Vth,
        0.125f * LOG2E);

    // pair-balanced causal flash: 8 pairs x 64 heads, 17 tiles per block
    flash_kernel<<<dim3(8, BH), 512, 0, stream>>>(Qh, Kh, Vth, AO);

    gemm_out<<<dim3((EE/128) * (MM/128)), 256, 0, stream>>>(AO, Woc, bo, (float*)d_out);
}

// Round 11
// 361.085 us; speedup vs baseline: 1.2138x; 1.0100x over previous
//
#include <hip/hip_runtime.h>
#include <hip/hip_bf16.h>
#include <cstdint>

// Problem constants
#define BB 4
#define TT 2048
#define EE 1024
#define HH 16
#define DD 64
#define BH (BB*HH)       // 64
#define MM (BB*TT)       // 8192 rows for projection GEMMs
#define KK 1024          // contraction dim for projections
#define KSTR 72          // flash K-tile LDS row stride (ushorts)
#define VSTR 136         // flash V-tile LDS row stride (ushorts)
#define LOG2E 1.44269504088896340736f

typedef __attribute__((ext_vector_type(8))) short short8;    // 8 x bf16
typedef __attribute__((ext_vector_type(4))) short short4_;   // 4 x bf16
typedef __attribute__((ext_vector_type(4))) float float4_;   // MFMA accumulator
typedef __attribute__((ext_vector_type(4))) ushort ushort4_;

__device__ __forceinline__ void gl_lds16(const void* g, void* l) {
    __builtin_amdgcn_global_load_lds(
        (const __attribute__((address_space(1))) void*)g,
        (__attribute__((address_space(3))) void*)l, 16, 0, 0);
}

__device__ __forceinline__ ushort f2bf(float v) {
    __hip_bfloat16 h = __float2bfloat16(v);
    return *(ushort*)&h;
}

// ---------------------------------------------------------------------------
// fp32 -> bf16 conversion (weights only). grid.y selects segment.
// ---------------------------------------------------------------------------
__global__ __launch_bounds__(256) void cvt_kernel(
    const float* __restrict__ s0, ushort* __restrict__ d0, int n0,
    const float* __restrict__ s1, ushort* __restrict__ d1, int n1,
    const float* __restrict__ s2, ushort* __restrict__ d2, int n2,
    const float* __restrict__ s3, ushort* __restrict__ d3, int n3)
{
    const float* s; ushort* d; int n;
    switch (blockIdx.y) {
        case 0: s = s0; d = d0; n = n0; break;
        case 1: s = s1; d = d1; n = n1; break;
        case 2: s = s2; d = d2; n = n2; break;
        default: s = s3; d = d3; n = n3; break;
    }
    int i = (blockIdx.x * 256 + threadIdx.x) * 4;
    if (i >= n) return;
    float4_ v = *(const float4_*)&s[i];
    ushort4_ o;
#pragma unroll
    for (int j = 0; j < 4; j++) o[j] = f2bf(v[j]);
    *(ushort4_*)&d[i] = o;
}

// ---------------------------------------------------------------------------
// MERGED Q/K/V projection GEMM.  1D grid + XCD-chunked bijective swizzle.
//
// Round-11 change: XOR-SWIZZLE the fp32 A tile (T2, rule-#21 form).  R10
// counters: SQ_LDS_BANK_CONFLICT tripled to 2.2e7 when A went fp32 — the
// [128][32-float] row is exactly 128 B (32 banks), so the fragment read
// r*32+quad*8 puts all 16 l15-lanes on the same 4-bank group (16-way).
// 2.2e7 cy / 256 CU ~ 26% of kernel cycles of serialized LDS traffic.
// Fix: gl_lds DEST stays linear; the per-lane GLOBAL SOURCE is permuted
// (chunk_src = chunk ^ (row&7)), and the fragment read applies the same
// XOR -> 16 lanes spread over 8 slots = 2-way = free.  W tile unchanged
// (m97-proven).  Everything else as R9/R10.
// C[n,e] = (sum_k A[n,k]*W[e,k] + bias[e])*scale
// z=0,1: scatter bf16 per-head [B*H, T, D];  z=2: transposed [B*H, D, T].
// ---------------------------------------------------------------------------
__global__ __launch_bounds__(256, 3) void gemm_qkv(
    const float* __restrict__ Aq, const float* __restrict__ Ak,
    const float* __restrict__ Av,
    const ushort* __restrict__ Wqc, const ushort* __restrict__ Wkc,
    const ushort* __restrict__ Wvc,
    const float* __restrict__ bq, const float* __restrict__ bk,
    const float* __restrict__ bv,
    ushort* __restrict__ Oq, ushort* __restrict__ Ok, ushort* __restrict__ Ov,
    float qscale)
{
    __shared__ __align__(16) float  Asf[128*32];   // fp32 A tile, 16 KB (swizzled)
    __shared__ __align__(16) ushort Bs [128*32];   // bf16 W tile,  8 KB

    const int bid = blockIdx.x;
    const int swz = (bid & 7) * 192 + (bid >> 3);
    const int z   = swz >> 9;          // 512 blocks per z
    const int rem = swz & 511;
    const int bx  = rem & 7;           // col-block (x fastest within chunk)
    const int by  = rem >> 3;          // row-block

    const float*  A    = (z == 0) ? Aq  : (z == 1) ? Ak  : Av;
    const ushort* W    = (z == 0) ? Wqc : (z == 1) ? Wkc : Wvc;
    const float*  bias = (z == 0) ? bq  : (z == 1) ? bk  : bv;
    ushort*       Cout = (z == 0) ? Oq  : (z == 1) ? Ok  : Ov;
    const float   scale = (z == 0) ? qscale : 1.0f;
    const bool    modeT = (z == 2);

    const int tid  = threadIdx.x;
    const int wave = tid >> 6;
    const int lane = tid & 63;
    const int l15  = lane & 15;
    const int quad = lane >> 4;
    const int wm   = wave & 1;   // row half
    const int wn   = wave >> 1;  // col half

    const long rowBase = (long)by * 128;
    const long colBase = (long)bx * 128;

    float4_ acc[4][4];
#pragma unroll
    for (int i = 0; i < 4; i++)
#pragma unroll
        for (int j = 0; j < 4; j++) acc[i][j] = float4_{0.f, 0.f, 0.f, 0.f};

    for (int k0 = 0; k0 < KK; k0 += 32) {
        __syncthreads();   // previous k-step's LDS reads done
        // A fp32, swizzled source: LDS slot (r, c) holds global chunk c^(r&7)
#pragma unroll
        for (int it = 0; it < 4; it++) {
            int idx = it * 256 + tid;
            int r = idx >> 3, c = idx & 7;
            int csrc = c ^ (r & 7);
            gl_lds16(A + (rowBase + r) * KK + k0 + csrc * 4, &Asf[idx * 4]);
        }
#pragma unroll
        for (int it = 0; it < 2; it++) {
            int idx = it * 256 + tid;
            int r = idx >> 2, c8 = (idx & 3) * 8;
            gl_lds16(W + (colBase + r) * KK + k0 + c8, &Bs[idx * 8]);
        }
        __syncthreads();

        // fragments: A read fp32+cvt with the same XOR; W plain bf16
        short8 af[4], bf[4];
#pragma unroll
        for (int mt = 0; mt < 4; mt++) {
            const int r = wm*64 + mt*16 + l15;
            const int s = r & 7;
            const float* arow = &Asf[r * 32];
            float4_ a0 = *(const float4_*)&arow[((2*quad    ) ^ s) * 4];
            float4_ a1 = *(const float4_*)&arow[((2*quad + 1) ^ s) * 4];
#pragma unroll
            for (int j = 0; j < 4; j++) {
                af[mt][j]     = (short)f2bf(a0[j]);
                af[mt][j + 4] = (short)f2bf(a1[j]);
            }
        }
#pragma unroll
        for (int nt = 0; nt < 4; nt++)
            bf[nt] = *(const short8*)&Bs[(wn*64 + nt*16 + l15) * 32 + quad*8];
#pragma unroll
        for (int mt = 0; mt < 4; mt++)
#pragma unroll
            for (int nt = 0; nt < 4; nt++)
                acc[mt][nt] = __builtin_amdgcn_mfma_f32_16x16x32_bf16(
                    af[mt], bf[nt], acc[mt][nt], 0, 0, 0);
    }

    // Epilogue: C/D layout col = lane&15, row = quad*4 + reg
#pragma unroll
    for (int nt = 0; nt < 4; nt++) {
        const long col = colBase + wn*64 + nt*16 + l15;
        const float bvv = bias[col];
        const long h = col >> 6, d = col & (DD - 1);
#pragma unroll
        for (int mt = 0; mt < 4; mt++) {
            const long row0 = rowBase + wm*64 + mt*16 + quad*4;
            if (modeT) {
                const long b = row0 >> 11, t0 = row0 & (TT - 1);
                ushort4_ pk;
#pragma unroll
                for (int i = 0; i < 4; i++) pk[i] = f2bf((acc[mt][nt][i] + bvv) * scale);
                *(ushort4_*)&Cout[((b*HH + h)*DD + d)*TT + t0] = pk;
            } else {
#pragma unroll
                for (int i = 0; i < 4; i++) {
                    const long row = row0 + i;
                    const long b = row >> 11, t = row & (TT - 1);
                    Cout[(((b*HH + h) * TT) + t) * DD + d] =
                        f2bf((acc[mt][nt][i] + bvv) * scale);
                }
            }
        }
    }
}

// ---------------------------------------------------------------------------
// Output GEMM: m97-form (BK=32, gl_lds both operands) + XCD swizzle.
// C fp32 row-major [MM, EE] = (AO @ Wo^T + bo)
// ---------------------------------------------------------------------------
__global__ __launch_bounds__(256, 3) void gemm_out(
    const ushort* __restrict__ A, const ushort* __restrict__ W,
    const float* __restrict__ bias, float* __restrict__ Cout)
{
    __shared__ __align__(16) ushort As[128*32];
    __shared__ __align__(16) ushort Bs[128*32];

    const int bid = blockIdx.x;
    const int swz = (bid & 7) * 64 + (bid >> 3);   // 512 blocks, 64/chunk
    const int bx  = swz & 7;
    const int by  = swz >> 3;

    const int tid  = threadIdx.x;
    const int wave = tid >> 6;
    const int lane = tid & 63;
    const int l15  = lane & 15;
    const int quad = lane >> 4;
    const int wm   = wave & 1;
    const int wn   = wave >> 1;

    const long rowBase = (long)by * 128;
    const long colBase = (long)bx * 128;

    float4_ acc[4][4];
#pragma unroll
    for (int i = 0; i < 4; i++)
#pragma unroll
        for (int j = 0; j < 4; j++) acc[i][j] = float4_{0.f, 0.f, 0.f, 0.f};

    for (int k0 = 0; k0 < KK; k0 += 32) {
        __syncthreads();
#pragma unroll
        for (int it = 0; it < 2; it++) {
            int idx = it * 256 + tid;
            int r   = idx >> 2;
            int c8  = (idx & 3) * 8;
            gl_lds16(A + (rowBase + r) * KK + k0 + c8, &As[idx * 8]);
            gl_lds16(W + (colBase + r) * KK + k0 + c8, &Bs[idx * 8]);
        }
        __syncthreads();

        short8 af[4], bf[4];
#pragma unroll
        for (int mt = 0; mt < 4; mt++)
            af[mt] = *(const short8*)&As[(wm*64 + mt*16 + l15) * 32 + quad*8];
#pragma unroll
        for (int nt = 0; nt < 4; nt++)
            bf[nt] = *(const short8*)&Bs[(wn*64 + nt*16 + l15) * 32 + quad*8];
#pragma unroll
        for (int mt = 0; mt < 4; mt++)
#pragma unroll
            for (int nt = 0; nt < 4; nt++)
                acc[mt][nt] = __builtin_amdgcn_mfma_f32_16x16x32_bf16(
                    af[mt], bf[nt], acc[mt][nt], 0, 0, 0);
    }

#pragma unroll
    for (int nt = 0; nt < 4; nt++) {
        const long col = colBase + wn*64 + nt*16 + l15;
        const float bv = bias[col];
#pragma unroll
        for (int mt = 0; mt < 4; mt++) {
            const long row0 = rowBase + wm*64 + mt*16 + quad*4;
#pragma unroll
            for (int i = 0; i < 4; i++)
                Cout[(row0 + i) * EE + col] = acc[mt][nt][i] + bv;
        }
    }
}

// ---------------------------------------------------------------------------
// Flash attention (causal). Q,K: [B*H, T, D] bf16; Vt: [B*H, D, T] bf16;
// AO: [B, T, E] bf16.  Q pre-scaled by 0.125*log2(e) -> softmax via exp2.
// (R10 form: pair-balanced 17-tile blocks, double-buffered K/V LDS with one
// barrier per tile, operand-swapped S^T = mfma(K,Q), scalar softmax state,
// P in registers.)
// ---------------------------------------------------------------------------
__global__ __launch_bounds__(512, 4) void flash_kernel(
    const ushort* __restrict__ Qh, const ushort* __restrict__ Kh,
    const ushort* __restrict__ Vt, ushort* __restrict__ AO)
{
    __shared__ __align__(16) ushort Ks[2][128*KSTR];   // [buf][key][d]  36.9 KB
    __shared__ __align__(16) ushort Vs[2][64*VSTR];    // [buf][d][key]  34.8 KB

    const int p   = blockIdx.x;                 // pair index 0..7
    const int bh  = blockIdx.y;                 // b*H + h
    const int tid = threadIdx.x;
    const int wave = tid >> 6, lane = tid & 63;
    const int l15 = lane & 15, quad = lane >> 4;

    const ushort* Qb = Qh + (long)bh * TT * DD;
    const ushort* Kb = Kh + (long)bh * TT * DD;
    const ushort* Vb = Vt + (long)bh * DD * TT;
    const int h = bh & (HH - 1);
    const int b = bh >> 4;

    // staging geometry (constant per thread)
    int kks[2], kss[2], dds[2], vss[2];
#pragma unroll
    for (int it = 0; it < 2; it++) {
        int c = it * 512 + tid;                 // 0..1023
        kks[it] = c >> 3; kss[it] = c & 7;      // K: key, 16B seg
        dds[it] = c >> 4; vss[it] = c & 15;     // V: d, 16B seg
    }

#pragma unroll
    for (int seg = 0; seg < 2; seg++) {
        const int qt  = (seg == 0) ? (15 - p) : p;   // heavy first
        const int nkt = qt + 1;

        // this segment's q-row (B-frag of swapped QK^T; also the output t)
        const int qrow = qt*128 + wave*16 + l15;
        short8 aq0 = *(const short8*)&Qb[(long)qrow * DD + quad*8];
        short8 aq1 = *(const short8*)&Qb[(long)qrow * DD + 32 + quad*8];

        float4_ o[4];
#pragma unroll
        for (int nt = 0; nt < 4; nt++) o[nt] = float4_{0.f, 0.f, 0.f, 0.f};
        float m_run = -INFINITY, l_run = 0.0f;

        // stage tile 0 -> buf 0
        short8 kreg[2], vreg[2];
#pragma unroll
        for (int it = 0; it < 2; it++) {
            kreg[it] = *(const short8*)&Kb[(long)kks[it] * DD + kss[it]*8];
            vreg[it] = *(const short8*)&Vb[(long)dds[it] * TT + vss[it]*8];
        }
        __syncthreads();   // all waves done reading every buffer (prev seg)
#pragma unroll
        for (int it = 0; it < 2; it++) {
            *(short8*)&Ks[0][kks[it]*KSTR + kss[it]*8] = kreg[it];
            *(short8*)&Vs[0][dds[it]*VSTR + vss[it]*8] = vreg[it];
        }
        __syncthreads();
        int cur = 0;

        for (int kt = 0; kt < nkt; kt++) {
            // prefetch next tile into regs (latency hides under compute)
            if (kt + 1 < nkt) {
                const long koff = (long)(kt+1) * 128;
#pragma unroll
                for (int it = 0; it < 2; it++) {
                    kreg[it] = *(const short8*)&Kb[(koff + kks[it]) * DD + kss[it]*8];
                    vreg[it] = *(const short8*)&Vb[(long)dds[it] * TT + koff + vss[it]*8];
                }
            }
            const ushort* ksb = &Ks[cur][0];
            const ushort* vsb = &Vs[cur][0];

            // S^T = mfma(K, Q): col = q = l15, row = key = quad*4 + i
            float4_ s[8];
            __builtin_amdgcn_s_setprio(1);
#pragma unroll
            for (int nt = 0; nt < 8; nt++) {
                short8 bk0 = *(const short8*)&ksb[(nt*16 + l15) * KSTR + quad*8];
                short8 bk1 = *(const short8*)&ksb[(nt*16 + l15) * KSTR + 32 + quad*8];
                float4_ acc = float4_{0.f, 0.f, 0.f, 0.f};
                acc = __builtin_amdgcn_mfma_f32_16x16x32_bf16(bk0, aq0, acc, 0,0,0);
                acc = __builtin_amdgcn_mfma_f32_16x16x32_bf16(bk1, aq1, acc, 0,0,0);
                s[nt] = acc;
            }
            __builtin_amdgcn_s_setprio(0);

            if (kt == nkt - 1) {   // only the diagonal tile crosses the mask
#pragma unroll
                for (int nt = 0; nt < 8; nt++) {
#pragma unroll
                    for (int i = 0; i < 4; i++) {
                        const int key = kt*128 + nt*16 + quad*4 + i;
                        if (key > qrow) s[nt][i] = -INFINITY;
                    }
                }
            }

            // row max: register tree over 32 keys + 2 cross-quad shfls
            float t8[8];
#pragma unroll
            for (int nt = 0; nt < 8; nt++)
                t8[nt] = fmaxf(fmaxf(s[nt][0], s[nt][1]), fmaxf(s[nt][2], s[nt][3]));
            float pm = fmaxf(fmaxf(fmaxf(t8[0], t8[1]), fmaxf(t8[2], t8[3])),
                             fmaxf(fmaxf(t8[4], t8[5]), fmaxf(t8[6], t8[7])));
            pm = fmaxf(pm, __shfl_xor(pm, 16));
            pm = fmaxf(pm, __shfl_xor(pm, 32));

            // T13 defer-max
            if (!__all(pm <= m_run + 8.0f)) {
                const float mnew = fmaxf(m_run, pm);
                const float alpha = exp2f(m_run - mnew);
                m_run = mnew;
                l_run *= alpha;
#pragma unroll
                for (int nt = 0; nt < 4; nt++)
#pragma unroll
                    for (int i = 0; i < 4; i++) o[nt][i] *= alpha;
            }

            // P = exp2(S - m): row sum + immediate bf16 pack
            float rs0 = 0.f, rs1 = 0.f, rs2 = 0.f, rs3 = 0.f;
            short8 pb[4];
#pragma unroll
            for (int c = 0; c < 4; c++) {
#pragma unroll
                for (int half = 0; half < 2; half++) {
                    const int nt = 2*c + half;
                    const float p0 = exp2f(s[nt][0] - m_run);
                    const float p1 = exp2f(s[nt][1] - m_run);
                    const float p2 = exp2f(s[nt][2] - m_run);
                    const float p3 = exp2f(s[nt][3] - m_run);
                    rs0 += p0; rs1 += p1; rs2 += p2; rs3 += p3;
                    pb[c][half*4 + 0] = (short)f2bf(p0);
                    pb[c][half*4 + 1] = (short)f2bf(p1);
                    pb[c][half*4 + 2] = (short)f2bf(p2);
                    pb[c][half*4 + 3] = (short)f2bf(p3);
                }
            }
            float rs = (rs0 + rs1) + (rs2 + rs3);
            rs += __shfl_xor(rs, 16);
            rs += __shfl_xor(rs, 32);
            l_run += rs;

            // O^T += V^T @ P^T, P from registers.
            __builtin_amdgcn_s_setprio(1);
#pragma unroll
            for (int c = 0; c < 4; c++) {
                const short8 bp = pb[c];
#pragma unroll
                for (int nt = 0; nt < 4; nt++) {
                    const ushort* vrow = &vsb[(nt*16 + l15) * VSTR];
                    short4_ lo = *(const short4_*)&vrow[(2*c    )*16 + quad*4];
                    short4_ hi = *(const short4_*)&vrow[(2*c + 1)*16 + quad*4];
                    short8 av;
                    av[0]=lo[0]; av[1]=lo[1]; av[2]=lo[2]; av[3]=lo[3];
                    av[4]=hi[0]; av[5]=hi[1]; av[6]=hi[2]; av[7]=hi[3];
                    o[nt] = __builtin_amdgcn_mfma_f32_16x16x32_bf16(av, bp, o[nt], 0,0,0);
                }
            }
            __builtin_amdgcn_s_setprio(0);

            // publish next tile into the other buffer; single barrier per tile
            if (kt + 1 < nkt) {
#pragma unroll
                for (int it = 0; it < 2; it++) {
                    *(short8*)&Ks[cur^1][kks[it]*KSTR + kss[it]*8] = kreg[it];
                    *(short8*)&Vs[cur^1][dds[it]*VSTR + vss[it]*8] = vreg[it];
                }
                __syncthreads();
                cur ^= 1;
            }
        }

        // epilogue: AO[b, t=qrow, h*64 + d] = o / l
        const float inv = 1.0f / l_run;
        const long rowOff = ((long)(b*TT + qrow)) * EE + h*64;
#pragma unroll
        for (int nt = 0; nt < 4; nt++) {
            ushort4_ pk;
#pragma unroll
            for (int i = 0; i < 4; i++) pk[i] = f2bf(o[nt][i] * inv);
            *(ushort4_*)&AO[rowOff + nt*16 + quad*4] = pk;
        }
    }
}

// ---------------------------------------------------------------------------
extern "C" void kernel_launch(void* const* d_in, const int* in_sizes, int n_in,
                              void* d_out, int out_size, void* d_ws, size_t ws_size,
                              hipStream_t stream)
{
    const float* query  = (const float*)d_in[0];
    const float* key_in = (const float*)d_in[1];
    const float* value  = (const float*)d_in[2];
    // d_in[3] = mask (int32 tril) — causal is hard-coded in flash_kernel
    const float* Wq = (const float*)d_in[4];
    const float* bq = (const float*)d_in[5];
    const float* Wk = (const float*)d_in[6];
    const float* bk = (const float*)d_in[7];
    const float* Wv = (const float*)d_in[8];
    const float* bv = (const float*)d_in[9];
    const float* Wo = (const float*)d_in[10];
    const float* bo = (const float*)d_in[11];

    ushort* ws = (ushort*)d_ws;
    const size_t NIN = (size_t)MM * KK;        // 8,388,608 elems
    const size_t NW  = (size_t)EE * KK;        // 1,048,576 elems (weights)
    ushort* Wqc = ws;                          // 2 MB each
    ushort* Wkc = Wqc + NW;
    ushort* Wvc = Wkc + NW;
    ushort* Woc = Wvc + NW;
    ushort* Qh  = Woc + NW;                    // 16 MB  [bh][t][d], pre-scaled
    ushort* Kh  = Qh + NIN;                    // 16 MB  [bh][t][d]
    ushort* Vth = Kh + NIN;                    // 16 MB  [bh][d][t]
    ushort* AO  = Vth + NIN;                   // 16 MB  [b][t][e]  (total 72 MB)

    const dim3 cvtW_grid(NW/1024, 4);

    // weights -> bf16 (one batched launch)
    cvt_kernel<<<cvtW_grid, 256, 0, stream>>>(Wq, Wqc, (int)NW, Wk, Wkc, (int)NW,
                                              Wv, Wvc, (int)NW, Wo, Woc, (int)NW);

    // Q/K/V projections merged, 1D grid with XCD-chunked swizzle
    gemm_qkv<<<dim3(3 * (EE/128) * (MM/128)), 256, 0, stream>>>(
        query, key_in, value, Wqc, Wkc, Wvc, bq, bk, bv, Qh, Kh, Vth,
        0.125f * LOG2E);

    // pair-balanced causal flash: 8 pairs x 64 heads, 17 tiles per block
    flash_kernel<<<dim3(8, BH), 512, 0, stream>>>(Qh, Kh, Vth, AO);

    gemm_out<<<dim3((EE/128) * (MM/128)), 256, 0, stream>>>(AO, Woc, bo, (float*)d_out);
}